// Round 1
// baseline (881.894 us; speedup 1.0000x reference)
//
#include <hip/hip_runtime.h>

// Pairwise interaction: out[b, p, e] = in[b, I[p], e] * in[b, J[p], e]
// B=4096, F=39, E=64, P = F*(F-1)/2 = 741 (strict upper triangle, row-major).
// Write-BW-bound: 777 MB out + 39 MB in => floor ~130-150 us at ~6 TB/s.

#define NF 39
#define NE 64
#define NP 741
#define NB 4096

// Compile-time pair table: packed (i*NE) | (j*NE << 16) float-offsets into the
// LDS-staged row. One dword load per pair, broadcast across the 16-lane group.
struct PairTab { unsigned int off[NP]; };
constexpr PairTab make_tab() {
    PairTab t{};
    int p = 0;
    for (int i = 0; i < NF; ++i)
        for (int j = i + 1; j < NF; ++j) {
            t.off[p] = (unsigned int)(i * NE) | ((unsigned int)(j * NE) << 16);
            ++p;
        }
    return t;
}
__constant__ PairTab TAB = make_tab();

__global__ __launch_bounds__(256) void pairwise_kernel(
        const float* __restrict__ in, float* __restrict__ out) {
    __shared__ float lds[NF * NE];  // 2496 floats = 9984 B

    const int b = blockIdx.x;
    const int t = threadIdx.x;

    // Stage this batch row into LDS, coalesced float4 (624 float4 total).
    const float4* in4 = (const float4*)(in + (size_t)b * (NF * NE));
    float4* lds4 = (float4*)lds;
    for (int k = t; k < (NF * NE) / 4; k += 256) lds4[k] = in4[k];
    __syncthreads();

    // 16 pair-groups x 16 float4-lanes. Each iteration: block writes 16
    // complete pairs = 4096 B contiguous; each wave writes 1024 B contiguous.
    const int e4   = (t & 15) * 4;  // float offset of this lane's float4 in the row
    const int psub = t >> 4;        // 0..15

    float* outb = out + (size_t)b * (NP * NE);

    for (int p = psub; p < NP; p += 16) {
        const unsigned int packed = TAB.off[p];
        const int offA = (int)(packed & 0xFFFFu);
        const int offB = (int)(packed >> 16);

        const float4 a = *(const float4*)(lds + offA + e4);
        const float4 c = *(const float4*)(lds + offB + e4);
        float4 r;
        r.x = a.x * c.x;
        r.y = a.y * c.y;
        r.z = a.z * c.z;
        r.w = a.w * c.w;
        *(float4*)(outb + p * NE + e4) = r;
    }
}

extern "C" void kernel_launch(void* const* d_in, const int* in_sizes, int n_in,
                              void* d_out, int out_size, void* d_ws, size_t ws_size,
                              hipStream_t stream) {
    const float* in = (const float*)d_in[0];
    float* out = (float*)d_out;
    pairwise_kernel<<<dim3(NB), dim3(256), 0, stream>>>(in, out);
}